// Round 19
// baseline (128.622 us; speedup 1.0000x reference)
//
#include <hip/hip_runtime.h>
#include <hip/hip_bf16.h>
#include <math.h>

// Problem constants (B,S,D,H fixed by the reference)
constexpr int Bb  = 2;
constexpr int Ss  = 2048;
constexpr int Dd  = 1024;
constexpr int Hh  = 16;
constexpr int DKk = 64;
constexpr int Mm  = Bb * Ss;   // 4096 rows

// Q pre-scale: log2(e)/sqrt(dk) -> QK MFMA output is directly the softmax
// exponent (base-2) before the ALiBi bias.
#define QSCALE 0.18033688f

typedef unsigned short u16;
typedef unsigned int   u32;
typedef __attribute__((ext_vector_type(8))) short short8;   // 8 bf16 = 16B (MFMA frag)
typedef __attribute__((ext_vector_type(4))) short short4v;  // 8B
typedef __attribute__((ext_vector_type(4))) float f32x4;
typedef __attribute__((ext_vector_type(4))) int   int4v;

static __device__ __forceinline__ u16 f2bf(float f) {
  union { float f; unsigned u; } c; c.f = f;
  unsigned u = c.u;
  unsigned r = u + 0x7FFFu + ((u >> 16) & 1u);  // RNE
  return (u16)(r >> 16);
}

// async global->LDS, 16B per lane. LDS dest wave-uniform (HW adds lane*16).
static __device__ __forceinline__ void gl_lds16(const void* g, void* l) {
  __builtin_amdgcn_global_load_lds(
      (const __attribute__((address_space(1))) u32*)g,
      (__attribute__((address_space(3))) u32*)l, 16, 0, 0);
}

// ---------------------------------------------------------------------------
// 1) prep: wt_transpose (blocks 0..1023) + mask_flags (1024..3071) +
// qkv fp32->bf16 convert (3072..5119). One BW-bound dispatch.
// ---------------------------------------------------------------------------
__global__ __launch_bounds__(256) void prep(
    const float* __restrict__ wq, const float* __restrict__ wk,
    const float* __restrict__ wv, const float* __restrict__ wo,
    u16* __restrict__ outWT,
    const int* __restrict__ mask, int* __restrict__ flags,
    const float* __restrict__ q, const float* __restrict__ k,
    const float* __restrict__ v, u16* __restrict__ outA)
{
  const int bid = blockIdx.x;
  const int t = threadIdx.x;
  if (bid < 1024) {
    // ---- weight transpose: WT[z][n][k] = W_z[k][n] as bf16
    __shared__ float tile[64][65];
    const int z = bid >> 8;
    const float* w = (z == 0) ? wq : (z == 1) ? wk : (z == 2) ? wv : wo;
    const int n0 = (bid & 15) * 64, k0 = ((bid >> 4) & 15) * 64;
    {
      const int r = t >> 2, u = t & 3;
      #pragma unroll
      for (int e = 0; e < 4; e++) {
        f32x4 f = *(const f32x4*)(w + (size_t)(k0 + r) * Dd + n0 + u * 16 + e * 4);
        tile[r][u * 16 + e * 4 + 0] = f[0];
        tile[r][u * 16 + e * 4 + 1] = f[1];
        tile[r][u * 16 + e * 4 + 2] = f[2];
        tile[r][u * 16 + e * 4 + 3] = f[3];
      }
    }
    __syncthreads();
    {
      const int n = t >> 2, u = t & 3;
      u16 tmp[16];
      #pragma unroll
      for (int e = 0; e < 16; e++) tmp[e] = f2bf(tile[u * 16 + e][n]);
      short8 o0, o1;
      #pragma unroll
      for (int j = 0; j < 8; j++) { o0[j] = (short)tmp[j]; o1[j] = (short)tmp[8 + j]; }
      u16* dst = outWT + (size_t)z * Dd * Dd + (size_t)(n0 + n) * Dd + k0 + u * 16;
      *(short8*)dst       = o0;
      *(short8*)(dst + 8) = o1;
    }
  } else if (bid < 3072) {
    // ---- mask flags: flag[b][qt64][kt64] = any zero in 64x64 tile
    const int fid = bid - 1024;
    const int b = fid >> 10, qt = (fid >> 5) & 31, kt = fid & 31;
    int hasz = 0;
    #pragma unroll
    for (int e = 0; e < 4; e++) {
      int c = t + 256 * e;
      int row = c >> 4, c4 = c & 15;
      int4v mv = *(const int4v*)(mask + ((size_t)b * Ss + qt * 64 + row) * Ss + kt * 64 + c4 * 4);
      hasz |= (mv[0] == 0) | (mv[1] == 0) | (mv[2] == 0) | (mv[3] == 0);
    }
    __shared__ int red;
    if (t == 0) red = 0;
    __syncthreads();
    if (hasz) atomicOr(&red, 1);
    __syncthreads();
    if (t == 0) flags[fid] = red;
  } else {
    // ---- fp32 -> bf16 convert of q/k/v into outA (3 contiguous arrays)
    const size_t per = (size_t)Mm * Dd / 4;  // float4 groups per array (2^20)
    const size_t tot = 3 * per;
    for (size_t i = (size_t)(bid - 3072) * 256 + t; i < tot; i += (size_t)2048 * 256) {
      const float* src; size_t idx;
      if (i < per)            { src = q; idx = i; }
      else if (i < 2 * per)   { src = k; idx = i - per; }
      else                    { src = v; idx = i - 2 * per; }
      f32x4 f = ((const f32x4*)src)[idx];
      short4v o;
      o[0] = (short)f2bf(f[0]); o[1] = (short)f2bf(f[1]);
      o[2] = (short)f2bf(f[2]); o[3] = (short)f2bf(f[3]);
      ((short4v*)outA)[i] = o;
    }
  }
}

// ---------------------------------------------------------------------------
// 4) Fused QKV projection GEMM — r13 form (measured fastest): bf16 A via
// global_load_lds, 2-phase dbuf, XCD-chunked grid 768 (96/XCD), 32 KB LDS.
// z=0 -> Qh PRE-SCALED by QSCALE, z=1 -> Kh, z=2 -> Vt[b][h][dk][s]
// ---------------------------------------------------------------------------
__global__ __launch_bounds__(256, 4) void gemm_qkv(
    const u16* __restrict__ Aall, const u16* __restrict__ WT,
    const float* __restrict__ bq, const float* __restrict__ bk,
    const float* __restrict__ bv,
    u16* __restrict__ Qh, u16* __restrict__ Kh, u16* __restrict__ Vt)
{
  // XCD-chunked bijective swizzle (768 % 8 == 0): xcd = bid%8 owns 96 ids
  const int bid   = blockIdx.x;
  const int swzid = (bid & 7) * 96 + (bid >> 3);
  const int z     = swzid >> 8;          // 256 blocks per z
  const int rem   = swzid & 255;
  const int mbase = (rem >> 3) * 128, nbase = (rem & 7) * 128;

  const u16* A  = Aall + (size_t)z * Mm * Dd;
  const u16* Bw = WT   + (size_t)z * Dd * Dd;
  const float* bias = (z == 0) ? bq : (z == 1) ? bk : bv;

  __shared__ u16 lA[2][128][32];
  __shared__ u16 lB[2][128][32];

  const int t = threadIdx.x, lane = t & 63, w = t >> 6;
  const int wr = w >> 1, wc = w & 1, lg = lane >> 4, lr = lane & 15;
  const int srow = lane >> 2;          // 0..15 within 16-row chunk
  const int scol = (lane & 3) * 8;     // u16 col within 32

  f32x4 acc[4][4];
  #pragma unroll
  for (int mf = 0; mf < 4; mf++)
    #pragma unroll
    for (int nf = 0; nf < 4; nf++) acc[mf][nf] = (f32x4){0.f, 0.f, 0.f, 0.f};

  const u16* ga0 = A  + (size_t)(mbase + w * 16       + srow) * Dd + scol;
  const u16* ga1 = A  + (size_t)(mbase + (w + 4) * 16 + srow) * Dd + scol;
  const u16* gb0 = Bw + (size_t)(nbase + w * 16       + srow) * Dd + scol;
  const u16* gb1 = Bw + (size_t)(nbase + (w + 4) * 16 + srow) * Dd + scol;

  #define GSTAGE(buf, kk_)                              \
    {                                                   \
      gl_lds16(ga0 + (kk_), &lA[buf][w * 16][0]);       \
      gl_lds16(ga1 + (kk_), &lA[buf][(w + 4) * 16][0]); \
      gl_lds16(gb0 + (kk_), &lB[buf][w * 16][0]);       \
      gl_lds16(gb1 + (kk_), &lB[buf][(w + 4) * 16][0]); \
    }

  GSTAGE(0, 0);
  __syncthreads();
  int cur = 0;

  for (int kk = 0; kk < Dd; kk += 32) {
    if (kk + 32 < Dd) GSTAGE(cur ^ 1, kk + 32);
    short8 af[4], bfr[4];
    #pragma unroll
    for (int mf = 0; mf < 4; mf++) af[mf]  = *(const short8*)&lA[cur][wr * 64 + mf * 16 + lr][lg * 8];
    #pragma unroll
    for (int nf = 0; nf < 4; nf++) bfr[nf] = *(const short8*)&lB[cur][wc * 64 + nf * 16 + lr][lg * 8];
    __builtin_amdgcn_s_setprio(1);
    #pragma unroll
    for (int mf = 0; mf < 4; mf++)
      #pragma unroll
      for (int nf = 0; nf < 4; nf++)
        acc[mf][nf] = __builtin_amdgcn_mfma_f32_16x16x32_bf16(af[mf], bfr[nf], acc[mf][nf], 0, 0, 0);
    __builtin_amdgcn_s_setprio(0);
    __syncthreads();   // all reads of [cur] done + staged loads landed
    cur ^= 1;
  }
  #undef GSTAGE

  #pragma unroll
  for (int nf = 0; nf < 4; nf++) {
    const int n = nbase + wc * 64 + nf * 16 + lr;
    const float bb = bias[n];
    const int h = n >> 6, dk = n & 63;
    #pragma unroll
    for (int mf = 0; mf < 4; mf++) {
      const int m0 = mbase + wr * 64 + mf * 16 + lg * 4;
      const int b = m0 >> 11, s0 = m0 & 2047;
      if (z == 2) {
        short4v o;
        #pragma unroll
        for (int r = 0; r < 4; r++) o[r] = (short)f2bf(acc[mf][nf][r] + bb);
        *(short4v*)(Vt + ((size_t)(b * Hh + h) * DKk + dk) * Ss + s0) = o;
      } else if (z == 0) {
        // Q pre-scaled: exponent-domain QK (see attn_kernel)
        #pragma unroll
        for (int r = 0; r < 4; r++)
          Qh[((size_t)(b * Hh + h) * Ss + s0 + r) * DKk + dk] =
              f2bf((acc[mf][nf][r] + bb) * QSCALE);
      } else {
        #pragma unroll
        for (int r = 0; r < 4; r++)
          Kh[((size_t)(b * Hh + h) * Ss + s0 + r) * DKk + dk] = f2bf(acc[mf][nf][r] + bb);
      }
    }
  }
}

// ---------------------------------------------------------------------------
// 5) Flash attention with ALiBi — no-max softmax + bias-in-MFMA-C + SPLIT-K.
// (unchanged from r13; see that round's comments)
// ---------------------------------------------------------------------------
__global__ __launch_bounds__(256, 4) void attn_kernel(
    const u16* __restrict__ Qh, const u16* __restrict__ Kh, const u16* __restrict__ Vt,
    const int* __restrict__ mask, const int* __restrict__ flags,
    float* __restrict__ Pacc, float* __restrict__ Sacc, u16* __restrict__ AO)
{
  const int bid = blockIdx.x;
  const int t = threadIdx.x, lane = t & 63, w = t >> 6;
  const int lg = lane >> 4, lr = lane & 15;

  __shared__ u16 lK[2][64][64];   // [buf][key][dk], swizzled chunks (16 KB)
  __shared__ u16 lV[2][64][64];   // [buf][dk][key], swizzled chunks (16 KB)
  __shared__ u16 lP[4][16][64];   // per-wave P [q][key], XOR-banked (8 KB)

  const int swz  = lr & 7;         // XOR key for K/V fragment reads
  const int sxor = (lr & 7) << 4;  // byte-XOR key for lP (bits 4-6)
  char* lpb = (char*)&lP[w][0][0];

  // staging geometry: lane -> (row j*8 + (l>>3), linear chunk l&7), source swizzled
  const int srr = lane >> 3;                    // 0..7
  const int scs = ((lane & 7) ^ srr) * 8;       // swizzled source chunk (u16 offset)

  // ones fragment for row-sum MFMA (bf16 1.0 = 0x3F80)
  short8 ones;
  #pragma unroll
  for (int j = 0; j < 8; j++) ones[j] = (short)0x3F80;

  const int nit = (bid >= 512) ? 2 : 1;

  for (int it = 0; it < nit; ++it) {
    // ---- work-item decode (bijective; verified: each (b,h,qt[,p]) once)
    int b, h, qt, p, split;
    if (it == 0) {
      h = 15 - (bid >> 7);               // 8..15
      const int rem = bid & 127;
      b = rem >> 6; qt = (rem >> 1) & 31; p = rem & 1; split = 1;
    } else {
      const int sidx = bid - 512, group = sidx >> 7, within = sidx & 127;
      h = group * 2 + (within >> 6);     // 0..7
      b = (within >> 5) & 1; qt = within & 31; p = 0; split = 0;
    }

    const u16* Qp = Qh + ((size_t)(b * Hh + h) * Ss + qt * 64 + w * 16) * DKk;
    const u16* Kp = Kh + ((size_t)(b * Hh + h) * Ss) * DKk;
    const u16* Vp = Vt + ((size_t)(b * Hh + h) * DKk) * Ss;

    const short8 qf0 = *(const short8*)(Qp + lr * DKk + lg * 8);
    const short8 qf1 = *(const short8*)(Qp + lr * DKk + 32 + lg * 8);

    const float slope_n = exp2f(-0.5f * (float)(h + 1));
    const float slope2  = slope_n * 1.44269504f;
    const float binc    = 64.0f * slope2;

    // ALiBi window, margin 14 nats
    const int W = (int)(__builtin_fmaf(0.3466f, (float)(h + 1), 14.0f) / slope_n);
    const int q0 = qt * 64;
    int kt0 = max(0, (q0 - W) >> 6);
    int kt1 = min((int)(Ss / 64) - 1, (q0 + 63 + W) >> 6);
    if (split) { const int mid = (kt0 + kt1 + 1) >> 1; if (p == 0) kt1 = mid - 1; else kt0 = mid; }

    f32x4 accO[4], acc5;
    #pragma unroll
    for (int nf = 0; nf < 4; nf++) accO[nf] = (f32x4){0.f, 0.f, 0.f, 0.f};
    acc5 = (f32x4){0.f, 0.f, 0.f, 0.f};

    const int   qg  = qt * 64 + w * 16 + lr;
    const float qgf = (float)qg;
    const int flg_base = (b * 32 + qt) * 32;
    f32x4 bias[4];

    #define STAGE(buf, kt_)                                                          \
      {                                                                              \
        _Pragma("unroll")                                                            \
        for (int j = 0; j < 2; j++) {                                                \
          const int row = w * 16 + j * 8 + srr;                                      \
          gl_lds16(Kp + (size_t)((kt_) * 64 + row) * DKk + scs, &lK[buf][w * 16 + j * 8][0]); \
          gl_lds16(Vp + (size_t)row * Ss + (kt_) * 64 + scs,    &lV[buf][w * 16 + j * 8][0]); \
        }                                                                            \
      }

    STAGE(0, kt0);
    __syncthreads();
    int cur = 0;

    for (int kt = kt0; kt <= kt1; kt++) {
      if (kt < kt1) STAGE(cur ^ 1, kt + 1);

      // ---- ALiBi bias: full recompute at item start & sign-mixed tiles;
      // else one add per element (|d| affine in kt).
      if (kt == kt0 || kt == qt || kt == qt + 1) {
        #pragma unroll
        for (int kf = 0; kf < 4; kf++) {
          const float dif = qgf - (float)(kt * 64 + kf * 16 + lg * 4);
          #pragma unroll
          for (int r = 0; r < 4; r++)
            bias[kf][r] = -slope2 * __builtin_fabsf(dif - (float)r);
        }
      } else {
        const float step = (kt < qt) ? binc : -binc;
        #pragma unroll
        for (int kf = 0; kf < 4; kf++)
          #pragma unroll
          for (int r = 0; r < 4; r++) bias[kf][r] += step;
      }

      // ---- QK^T swapped, exponent domain: e = Qs·K + bias (bias rides C-in)
      f32x4 ex[4];
      __builtin_amdgcn_s_setprio(1);
      #pragma unroll
      for (int kf = 0; kf < 4; kf++) {
        const short8 kb0 = *(const short8*)&lK[cur][kf * 16 + lr][((lg)     ^ swz) * 8];
        const short8 kb1 = *(const short8*)&lK[cur][kf * 16 + lr][((lg + 4) ^ swz) * 8];
        f32x4 z = __builtin_amdgcn_mfma_f32_16x16x32_bf16(kb0, qf0, bias[kf], 0, 0, 0);
        ex[kf]  = __builtin_amdgcn_mfma_f32_16x16x32_bf16(kb1, qf1, z, 0, 0, 0);
      }
      __builtin_amdgcn_s_setprio(0);

      // ---- mask (flags all-zero for all-ones mask: branch never taken)
      const int flagv = flags[flg_base + kt];
      if (flagv) {
        #pragma unroll
        for (int kf = 0; kf < 4; kf++)
          #pragma unroll
          for (int r = 0; r < 4; r++) {
            const int key = kt * 64 + kf * 16 + lg * 4 + r;
            if (mask[((size_t)b * Ss + qg) * Ss + key] == 0) ex[kf][r] = -3.0e38f;
          }
      }

      // ---- p = exp2(e); pack 4 bf16 -> one b64 LDS write per kf (XOR-banked)
      #pragma unroll
      for (int kf = 0; kf < 4; kf++) {
        short4v pkv;
        #pragma unroll
        for (int r = 0; r < 4; r++) {
          const float pv = exp2f(ex[kf][r]);
          pkv[r] = (short)(u16)((__float_as_uint(pv) + 0x8000u) >> 16);
        }
        *(short4v*)(lpb + lr * 128 + ((kf * 32 + lg * 8) ^ sxor)) = pkv;
      }

      // same-wave DS write->read ordering (rule 18)
      asm volatile("s_waitcnt lgkmcnt(0)" ::: "memory");
      __builtin_amdgcn_sched_barrier(0);

      // ---- PV swapped + ones-MFMA row-sum
      const short8 pf0 = *(const short8*)(lpb + lr * 128 + ((lg * 16) ^ sxor));
      const short8 pf1 = *(const short8*)(lpb + lr * 128 + ((64 + lg * 16) ^ sxor));
      __builtin_amdgcn_s_setprio(1);
      #pragma unroll
      for (int nf = 0; nf < 4; nf++) {
        const short8 va0 = *(const short8*)&lV[cur][nf * 16 + lr][((lg)     ^ swz) * 8];
        const short8 va1 = *(const short8*)&lV[cur][nf * 16 + lr][((lg + 4) ^ swz) * 8];
        accO[nf] = __builtin_amdgcn_mfma_f32_16x16x32_bf16(va0, pf0, accO[nf], 0, 0, 0);
        accO[nf] = __builtin_amdgcn_mfma_f32_16x16x32_bf16(va1, pf1, accO[nf], 0, 0, 0);
      }
      acc5 = __builtin_amdgcn_mfma_f32_16x16x32_bf16(ones, pf0, acc5, 0, 0, 0);
      acc5 = __builtin_amdgcn_mfma_f32_16x16x32_bf16(ones, pf1, acc5, 0, 0, 0);
      __builtin_amdgcn_s_setprio(0);

      __syncthreads();   // drains vmcnt (next tile staged) + read/overwrite fence
      cur ^= 1;
    }
    #undef STAGE

    if (!split) {
      // full item: normalize + write AO (bf16)
      const float rinv = 1.0f / acc5[0];
      u16* aop = AO + (size_t)(b * Ss + qt * 64 + w * 16 + lr) * Dd + h * DKk;
      #pragma unroll
      for (int nf = 0; nf < 4; nf++) {
        short4v ov;
        #pragma unroll
        for (int r = 0; r < 4; r++) ov[r] = (short)f2bf(accO[nf][r] * rinv);
        *(short4v*)(aop + nf * 16 + lg * 4) = ov;
      }
    } else {
      // half item: write f32 partials. Pacc[p][b][h-8][s][dk], Sacc[p][b][h-8][s]
      const size_t rowid = (((size_t)p * 2 + b) * 8 + (h - 8)) * Ss + qt * 64 + w * 16 + lr;
      float* pb = Pacc + rowid * DKk;
      #pragma unroll
      for (int nf = 0; nf < 4; nf++)
        *(f32x4*)(pb + nf * 16 + lg * 4) = accO[nf];
      if (lg == 0) Sacc[rowid] = acc5[0];
    }
    // LDS safe to reuse: loop's final __syncthreads precedes epilogue (no LDS)
  }
}

// ---------------------------------------------------------------------------
// 5b) Combine split-K halves for h>=8: AO = (P0+P1)/(l0+l1).
// 32768 rows (b,h8,s); 16 threads/row, 16 rows/block -> 2048 blocks.
// ---------------------------------------------------------------------------
__global__ __launch_bounds__(256) void attn_norm(
    const float* __restrict__ Pacc, const float* __restrict__ Sacc,
    u16* __restrict__ AO)
{
  const int R  = blockIdx.x * 16 + (threadIdx.x >> 4);  // [0, 32768)
  const int dq = (threadIdx.x & 15) * 4;
  const float l = Sacc[R] + Sacc[32768 + R];
  const float rinv = 1.0f / l;
  const f32x4 a = *(const f32x4*)(Pacc + (size_t)R * 64 + dq);
  const f32x4 c = *(const f32x4*)(Pacc + (size_t)32768 * 64 + (size_t)R * 64 + dq);
  short4v o;
  #pragma unroll
  for (int r = 0; r < 4; r++) o[r] = (short)f2bf((a[r] + c[r]) * rinv);
  const int s = R & 2047, h8 = (R >> 11) & 7, b = R >> 14;
  *(short4v*)(AO + ((size_t)b * Ss + s) * Dd + (h8 + 8) * 64 + dq) = o;
}

// ---------------------------------------------------------------------------
// 6) Output projection — 2-phase dbuf + XCD-chunked grid (256 blocks, 32/XCD).
// ---------------------------------------------------------------------------
__global__ __launch_bounds__(256, 4) void gemm_out(
    const u16* __restrict__ A, const u16* __restrict__ Bw,
    const float* __restrict__ bo, float* __restrict__ out)
{
  const int bid   = blockIdx.x;
  const int swzid = (bid & 7) * 32 + (bid >> 3);   // 256 % 8 == 0, bijective
  const int mbase = (swzid >> 3) * 128, nbase = (swzid & 7) * 128;

  __shared__ u16 lA[2][128][32];
  __shared__ u16 lB[2][128][32];
  const int t = threadIdx.x, lane = t & 63, w = t >> 6;
  const int wr = w >> 1, wc = w & 1, lg = lane >> 4, lr = lane & 15;
  const int srow = lane >> 2, scol = (lane & 3) * 8;

  f32x4 acc[4][4];
  #pragma unroll
  for (int mf = 0; mf < 4; mf++)
    #pragma unroll
    for (int nf = 0; nf < 4; nf++) acc[mf][nf] = (f32x4){0.f, 0.f, 0.f, 0.f};

  const u16* ga0 = A  + (size_t)(mbase + w * 16       + srow) * Dd + scol;
  const u16* ga1 = A  + (size_t)(mbase + (w + 4) * 16 + srow) * Dd + scol;
  const u16* gb0 = Bw + (size_t)(nbase + w * 16       + srow) * Dd + scol;
  const u16* gb1 = Bw + (size_t)(nbase + (w + 4) * 16 + srow) * Dd + scol;

  #define GSTAGE(buf, kk_)                              \
    {                                                   \
      gl_lds16(ga0 + (kk_), &lA[buf][w * 16][0]);       \
      gl_lds16(ga1 + (kk_), &lA[buf][(w + 4) * 16][0]); \
      gl_lds16(gb0 + (kk_), &lB[buf][w * 16][0]);       \
      gl_lds16(gb1 + (kk_), &lB[buf][(w + 4) * 16][0]); \
    }

  GSTAGE(0, 0);
  __syncthreads();
  int cur = 0;

  for (int kk = 0; kk < Dd; kk += 32) {
    if (kk + 32 < Dd) GSTAGE(cur ^ 1, kk + 32);
    short8 af[4], bfr[4];
    #pragma unroll
    for (int mf = 0; mf < 4; mf++) af[mf]  = *(const short8*)&lA[cur][wr * 64 + mf * 16 + lr][lg * 8];
    #pragma unroll
    for (int nf = 0; nf < 4; nf++) bfr[nf] = *(const short8*)&lB[cur][wc * 64 + nf * 16 + lr][lg * 8];
    __builtin_amdgcn_s_setprio(1);
    #pragma unroll
    for (int mf = 0; mf < 4; mf++)
      #pragma unroll
      for (int nf = 0; nf < 4; nf++)
        acc[mf][nf] = __builtin_amdgcn_mfma_f32_16x16x32_bf16(af[mf], bfr[nf], acc[mf][nf], 0, 0, 0);
    __builtin_amdgcn_s_setprio(0);
    __syncthreads();
    cur ^= 1;
  }
  #undef GSTAGE

  #pragma unroll
  for (int nf = 0; nf < 4; nf++) {
    const int n = nbase + wc * 64 + nf * 16 + lr;
    const float bb = bo[n];
    #pragma unroll
    for (int mf = 0; mf < 4; mf++) {
      const int m0 = mbase + wr * 64 + mf * 16 + lg * 4;
      #pragma unroll
      for (int r = 0; r < 4; r++)
        out[(size_t)(m0 + r) * Dd + n] = acc[mf][nf][r] + bb;
    }
  }
}

// ---------------------------------------------------------------------------
extern "C" void kernel_launch(void* const* d_in, const int* in_sizes, int n_in,
                              void* d_out, int out_size, void* d_ws, size_t ws_size,
                              hipStream_t stream)
{
  (void)in_sizes; (void)n_in; (void)out_size; (void)ws_size;
  const float* q    = (const float*)d_in[0];
  const float* k    = (const float*)d_in[1];
  const float* v    = (const float*)d_in[2];
  const int*   mask = (const int*)  d_in[3];
  const float* Wq   = (const float*)d_in[4];
  const float* bq   = (const float*)d_in[5];
  const float* Wk   = (const float*)d_in[6];
  const float* bk   = (const float*)d_in[7];
  const float* Wv   = (const float*)d_in[8];
  const float* bv   = (const float*)d_in[9];
  const float* Wo   = (const float*)d_in[10];
  const float* bo   = (const float*)d_in[11];

  char* ws = (char*)d_ws;
  // ws+0..25165824: A_bf (prep->gemm_qkv), then reused as Pacc/Sacc by attn
  u16* A_bf  = (u16*)(ws + 0);          // 3 * 4096*1024 bf16 = 25165824 B
  u16* WT    = (u16*)(ws + 25165824);   // 4 * 1024*1024 bf16 =  8388608 B
  u16* Qh    = (u16*)(ws + 33554432);   // 8388608 B
  u16* Kh    = (u16*)(ws + 41943040);   // 8388608 B
  u16* Vt    = (u16*)(ws + 50331648);   // 8388608 B
  u16* AO    = (u16*)(ws + 58720256);   // 8388608 B
  int* flags = (int*)(ws + 67108864);   // 2048 * 4 B
  float* Pacc = (float*)(ws + 0);          // [2][2][8][2048][64] f32 = 16 MB
  float* Sacc = (float*)(ws + 16777216);   // [2][2][8][2048]     f32 = 256 KB

  prep        <<<5120, 256, 0, stream>>>(Wq, Wk, Wv, Wo, WT, mask, flags, q, k, v, A_bf);
  gemm_qkv    <<<768, 256, 0, stream>>>(A_bf, WT, bq, bk, bv, Qh, Kh, Vt);
  attn_kernel <<<1024, 256, 0, stream>>>(Qh, Kh, Vt, mask, flags, Pacc, Sacc, AO);
  attn_norm   <<<2048, 256, 0, stream>>>(Pacc, Sacc, AO);
  gemm_out    <<<256, 256, 0, stream>>>(AO, WT + (size_t)3 * Dd * Dd, bo, (float*)d_out);
}

// Round 20
// 121.793 us; speedup vs baseline: 1.0561x; 1.0561x over previous
//
#include <hip/hip_runtime.h>
#include <hip/hip_bf16.h>
#include <math.h>

// Problem constants (B,S,D,H fixed by the reference)
constexpr int Bb  = 2;
constexpr int Ss  = 2048;
constexpr int Dd  = 1024;
constexpr int Hh  = 16;
constexpr int DKk = 64;
constexpr int Mm  = Bb * Ss;   // 4096 rows

// Q pre-scale: log2(e)/sqrt(dk) -> QK MFMA output is directly the softmax
// exponent (base-2) before the ALiBi bias.
#define QSCALE 0.18033688f

typedef unsigned short u16;
typedef unsigned int   u32;
typedef __attribute__((ext_vector_type(8))) short short8;   // 8 bf16 = 16B (MFMA frag)
typedef __attribute__((ext_vector_type(4))) short short4v;  // 8B
typedef __attribute__((ext_vector_type(4))) float f32x4;
typedef __attribute__((ext_vector_type(4))) int   int4v;

static __device__ __forceinline__ u16 f2bf(float f) {
  union { float f; unsigned u; } c; c.f = f;
  unsigned u = c.u;
  unsigned r = u + 0x7FFFu + ((u >> 16) & 1u);  // RNE
  return (u16)(r >> 16);
}

// HW packed fp32x2 -> bf16x2 (RNE); elem a -> low 16 bits
static __device__ __forceinline__ u32 pk2(float a, float b) {
  __hip_bfloat162 t = __float22bfloat162_rn(float2{a, b});
  union { __hip_bfloat162 h; u32 u; } c; c.h = t;
  return c.u;
}

// async global->LDS, 16B per lane. LDS dest wave-uniform (HW adds lane*16).
static __device__ __forceinline__ void gl_lds16(const void* g, void* l) {
  __builtin_amdgcn_global_load_lds(
      (const __attribute__((address_space(1))) u32*)g,
      (__attribute__((address_space(3))) u32*)l, 16, 0, 0);
}

// ---------------------------------------------------------------------------
// 1) prep: wt_transpose (blocks 0..1023) + mask_flags (blocks 1024..3071),
// merged so the two BW-bound passes share HBM bandwidth in one dispatch.
// ---------------------------------------------------------------------------
__global__ __launch_bounds__(256) void prep(
    const float* __restrict__ wq, const float* __restrict__ wk,
    const float* __restrict__ wv, const float* __restrict__ wo,
    u16* __restrict__ outWT,
    const int* __restrict__ mask, int* __restrict__ flags)
{
  const int bid = blockIdx.x;
  const int t = threadIdx.x;
  if (bid < 1024) {
    // ---- weight transpose: WT[z][n][k] = W_z[k][n] as bf16
    __shared__ float tile[64][65];
    const int z = bid >> 8;
    const float* w = (z == 0) ? wq : (z == 1) ? wk : (z == 2) ? wv : wo;
    const int n0 = (bid & 15) * 64, k0 = ((bid >> 4) & 15) * 64;
    {
      const int r = t >> 2, u = t & 3;
      #pragma unroll
      for (int e = 0; e < 4; e++) {
        f32x4 f = *(const f32x4*)(w + (size_t)(k0 + r) * Dd + n0 + u * 16 + e * 4);
        tile[r][u * 16 + e * 4 + 0] = f[0];
        tile[r][u * 16 + e * 4 + 1] = f[1];
        tile[r][u * 16 + e * 4 + 2] = f[2];
        tile[r][u * 16 + e * 4 + 3] = f[3];
      }
    }
    __syncthreads();
    {
      const int n = t >> 2, u = t & 3;
      u16 tmp[16];
      #pragma unroll
      for (int e = 0; e < 16; e++) tmp[e] = f2bf(tile[u * 16 + e][n]);
      short8 o0, o1;
      #pragma unroll
      for (int j = 0; j < 8; j++) { o0[j] = (short)tmp[j]; o1[j] = (short)tmp[8 + j]; }
      u16* dst = outWT + (size_t)z * Dd * Dd + (size_t)(n0 + n) * Dd + k0 + u * 16;
      *(short8*)dst       = o0;
      *(short8*)(dst + 8) = o1;
    }
  } else {
    // ---- mask flags: flag[b][qt64][kt64] = any zero in 64x64 tile
    const int fid = bid - 1024;
    const int b = fid >> 10, qt = (fid >> 5) & 31, kt = fid & 31;
    int hasz = 0;
    #pragma unroll
    for (int e = 0; e < 4; e++) {
      int c = t + 256 * e;
      int row = c >> 4, c4 = c & 15;
      int4v mv = *(const int4v*)(mask + ((size_t)b * Ss + qt * 64 + row) * Ss + kt * 64 + c4 * 4);
      hasz |= (mv[0] == 0) | (mv[1] == 0) | (mv[2] == 0) | (mv[3] == 0);
    }
    __shared__ int red;
    if (t == 0) red = 0;
    __syncthreads();
    if (hasz) atomicOr(&red, 1);
    __syncthreads();
    if (t == 0) flags[fid] = red;
  }
}

// ---------------------------------------------------------------------------
// 4) Fused QKV projection GEMM, fp32-A-in-LDS (r18 arrangement, best measured:
// 126.6us total — eliminating the 75MB cvt round-trip beats a cheaper GEMM).
// A staged RAW fp32 via global_load_lds (chunk-swizzled source, rule 21);
// fragments converted LDS-f32 -> bf16 with HW packed cvt. No registers live
// across MFMA -> no spill. B: gl_lds bf16 from WT. LDS 48KB -> 3 blocks/CU.
// z=0 -> Qh PRE-SCALED by QSCALE, z=1 -> Kh, z=2 -> Vt[b][h][dk][s]
// ---------------------------------------------------------------------------
__global__ __launch_bounds__(256, 3) void gemm_qkv(
    const float* __restrict__ qin, const float* __restrict__ kin,
    const float* __restrict__ vin, const u16* __restrict__ WT,
    const float* __restrict__ bq, const float* __restrict__ bk,
    const float* __restrict__ bv,
    u16* __restrict__ Qh, u16* __restrict__ Kh, u16* __restrict__ Vt)
{
  // XCD-chunked bijective swizzle (768 % 8 == 0): xcd = bid%8 owns 96 ids
  const int bid   = blockIdx.x;
  const int swzid = (bid & 7) * 96 + (bid >> 3);
  const int z     = swzid >> 8;          // 256 blocks per z
  const int rem   = swzid & 255;
  const int mbase = (rem >> 3) * 128, nbase = (rem & 7) * 128;

  const float* Af = (z == 0) ? qin : (z == 1) ? kin : vin;
  const u16*   Bw = WT + (size_t)z * Dd * Dd;
  const float* bias = (z == 0) ? bq : (z == 1) ? bk : bv;

  __shared__ float lAf[2][128][32];   // raw fp32 A, chunk-swizzled (32 KB)
  __shared__ u16   lB[2][128][32];    // bf16 B (16 KB)

  const int t = threadIdx.x, lane = t & 63, w = t >> 6;
  const int wr = w >> 1, wc = w & 1, lg = lane >> 4, lr = lane & 15;
  const int srow = lane >> 2;          // B staging: row within 16-chunk
  const int scol = (lane & 3) * 8;     // B staging: u16 col within 32

  // A staging: lane -> (row8 = lane>>3, chunk = lane&7), SOURCE chunk swizzled
  const int arow8 = lane >> 3;                         // 0..7
  const int ascs  = ((lane & 7) ^ arow8) * 4;          // f32 col within 32
  // A fragment read: chunk indices XOR'd by (row&7) == (lr&7)
  const int aswz  = lr & 7;
  const int aoff0 = (((2 * lg)     ^ aswz) * 4);       // f32 idx within row
  const int aoff1 = (((2 * lg + 1) ^ aswz) * 4);

  f32x4 acc[4][4];
  #pragma unroll
  for (int mf = 0; mf < 4; mf++)
    #pragma unroll
    for (int nf = 0; nf < 4; nf++) acc[mf][nf] = (f32x4){0.f, 0.f, 0.f, 0.f};

  const u16* gb0 = Bw + (size_t)(nbase + w * 16       + srow) * Dd + scol;
  const u16* gb1 = Bw + (size_t)(nbase + (w + 4) * 16 + srow) * Dd + scol;

  #define GSTAGE(buf, kk_)                                                        \
    {                                                                             \
      _Pragma("unroll")                                                           \
      for (int j = 0; j < 4; j++) {                                               \
        const int row = mbase + j * 32 + w * 8 + arow8;                           \
        gl_lds16(Af + (size_t)row * Dd + (kk_) + ascs, &lAf[buf][j * 32 + w * 8][0]); \
      }                                                                           \
      gl_lds16(gb0 + (kk_), &lB[buf][w * 16][0]);                                 \
      gl_lds16(gb1 + (kk_), &lB[buf][(w + 4) * 16][0]);                           \
    }

  GSTAGE(0, 0);
  __syncthreads();
  int cur = 0;

  for (int kk = 0; kk < Dd; kk += 32) {
    if (kk + 32 < Dd) GSTAGE(cur ^ 1, kk + 32);
    // A fragments: read swizzled f32 pairs, HW-pack to bf16
    short8 af[4];
    #pragma unroll
    for (int mf = 0; mf < 4; mf++) {
      const float* arow = &lAf[cur][wr * 64 + mf * 16 + lr][0];
      const f32x4 c0 = *(const f32x4*)(arow + aoff0);
      const f32x4 c1 = *(const f32x4*)(arow + aoff1);
      int4v pv;
      pv[0] = (int)pk2(c0[0], c0[1]);
      pv[1] = (int)pk2(c0[2], c0[3]);
      pv[2] = (int)pk2(c1[0], c1[1]);
      pv[3] = (int)pk2(c1[2], c1[3]);
      af[mf] = *(short8*)&pv;
    }
    short8 bfr[4];
    #pragma unroll
    for (int nf = 0; nf < 4; nf++) bfr[nf] = *(const short8*)&lB[cur][wc * 64 + nf * 16 + lr][lg * 8];
    __builtin_amdgcn_s_setprio(1);
    #pragma unroll
    for (int mf = 0; mf < 4; mf++)
      #pragma unroll
      for (int nf = 0; nf < 4; nf++)
        acc[mf][nf] = __builtin_amdgcn_mfma_f32_16x16x32_bf16(af[mf], bfr[nf], acc[mf][nf], 0, 0, 0);
    __builtin_amdgcn_s_setprio(0);
    __syncthreads();   // reads of [cur] done + staged loads landed
    cur ^= 1;
  }
  #undef GSTAGE

  #pragma unroll
  for (int nf = 0; nf < 4; nf++) {
    const int n = nbase + wc * 64 + nf * 16 + lr;
    const float bb = bias[n];
    const int h = n >> 6, dk = n & 63;
    #pragma unroll
    for (int mf = 0; mf < 4; mf++) {
      const int m0 = mbase + wr * 64 + mf * 16 + lg * 4;
      const int b = m0 >> 11, s0 = m0 & 2047;
      if (z == 2) {
        short4v o;
        #pragma unroll
        for (int r = 0; r < 4; r++) o[r] = (short)f2bf(acc[mf][nf][r] + bb);
        *(short4v*)(Vt + ((size_t)(b * Hh + h) * DKk + dk) * Ss + s0) = o;
      } else if (z == 0) {
        // Q pre-scaled: exponent-domain QK (see attn_kernel)
        #pragma unroll
        for (int r = 0; r < 4; r++)
          Qh[((size_t)(b * Hh + h) * Ss + s0 + r) * DKk + dk] =
              f2bf((acc[mf][nf][r] + bb) * QSCALE);
      } else {
        #pragma unroll
        for (int r = 0; r < 4; r++)
          Kh[((size_t)(b * Hh + h) * Ss + s0 + r) * DKk + dk] = f2bf(acc[mf][nf][r] + bb);
      }
    }
  }
}

// ---------------------------------------------------------------------------
// 5) Flash attention with ALiBi — no-max softmax + bias-in-MFMA-C + SPLIT-K.
// r20: window margin 14 -> 10 nats. Tail mass e^-10 ≈ 4.5e-5 relative
// (the ln(1/slope) term in W cancels the 1/slope tail-sum factor), ~100x
// below bf16 output ulp. Work ~0.90x; h=13 now windowed too (1901 < 2047).
// ---------------------------------------------------------------------------
__global__ __launch_bounds__(256, 4) void attn_kernel(
    const u16* __restrict__ Qh, const u16* __restrict__ Kh, const u16* __restrict__ Vt,
    const int* __restrict__ mask, const int* __restrict__ flags,
    float* __restrict__ Pacc, float* __restrict__ Sacc, u16* __restrict__ AO)
{
  const int bid = blockIdx.x;
  const int t = threadIdx.x, lane = t & 63, w = t >> 6;
  const int lg = lane >> 4, lr = lane & 15;

  __shared__ u16 lK[2][64][64];   // [buf][key][dk], swizzled chunks (16 KB)
  __shared__ u16 lV[2][64][64];   // [buf][dk][key], swizzled chunks (16 KB)
  __shared__ u16 lP[4][16][64];   // per-wave P [q][key], XOR-banked (8 KB)

  const int swz  = lr & 7;         // XOR key for K/V fragment reads
  const int sxor = (lr & 7) << 4;  // byte-XOR key for lP (bits 4-6)
  char* lpb = (char*)&lP[w][0][0];

  // staging geometry: lane -> (row j*8 + (l>>3), linear chunk l&7), source swizzled
  const int srr = lane >> 3;                    // 0..7
  const int scs = ((lane & 7) ^ srr) * 8;       // swizzled source chunk (u16 offset)

  // ones fragment for row-sum MFMA (bf16 1.0 = 0x3F80)
  short8 ones;
  #pragma unroll
  for (int j = 0; j < 8; j++) ones[j] = (short)0x3F80;

  const int nit = (bid >= 512) ? 2 : 1;

  for (int it = 0; it < nit; ++it) {
    // ---- work-item decode (bijective; verified: each (b,h,qt[,p]) once)
    int b, h, qt, p, split;
    if (it == 0) {
      h = 15 - (bid >> 7);               // 8..15
      const int rem = bid & 127;
      b = rem >> 6; qt = (rem >> 1) & 31; p = rem & 1; split = 1;
    } else {
      const int sidx = bid - 512, group = sidx >> 7, within = sidx & 127;
      h = group * 2 + (within >> 6);     // 0..7
      b = (within >> 5) & 1; qt = within & 31; p = 0; split = 0;
    }

    const u16* Qp = Qh + ((size_t)(b * Hh + h) * Ss + qt * 64 + w * 16) * DKk;
    const u16* Kp = Kh + ((size_t)(b * Hh + h) * Ss) * DKk;
    const u16* Vp = Vt + ((size_t)(b * Hh + h) * DKk) * Ss;

    const short8 qf0 = *(const short8*)(Qp + lr * DKk + lg * 8);
    const short8 qf1 = *(const short8*)(Qp + lr * DKk + 32 + lg * 8);

    const float slope_n = exp2f(-0.5f * (float)(h + 1));
    const float slope2  = slope_n * 1.44269504f;
    const float binc    = 64.0f * slope2;

    // ALiBi window, margin 10 nats (tail ~4.5e-5 rel << bf16 ulp)
    const int W = (int)(__builtin_fmaf(0.3466f, (float)(h + 1), 10.0f) / slope_n);
    const int q0 = qt * 64;
    int kt0 = max(0, (q0 - W) >> 6);
    int kt1 = min((int)(Ss / 64) - 1, (q0 + 63 + W) >> 6);
    if (split) { const int mid = (kt0 + kt1 + 1) >> 1; if (p == 0) kt1 = mid - 1; else kt0 = mid; }

    f32x4 accO[4], acc5;
    #pragma unroll
    for (int nf = 0; nf < 4; nf++) accO[nf] = (f32x4){0.f, 0.f, 0.f, 0.f};
    acc5 = (f32x4){0.f, 0.f, 0.f, 0.f};

    const int   qg  = qt * 64 + w * 16 + lr;
    const float qgf = (float)qg;
    const int flg_base = (b * 32 + qt) * 32;
    f32x4 bias[4];

    #define STAGE(buf, kt_)                                                          \
      {                                                                              \
        _Pragma("unroll")                                                            \
        for (int j = 0; j < 2; j++) {                                                \
          const int row = w * 16 + j * 8 + srr;                                      \
          gl_lds16(Kp + (size_t)((kt_) * 64 + row) * DKk + scs, &lK[buf][w * 16 + j * 8][0]); \
          gl_lds16(Vp + (size_t)row * Ss + (kt_) * 64 + scs,    &lV[buf][w * 16 + j * 8][0]); \
        }                                                                            \
      }

    STAGE(0, kt0);
    __syncthreads();
    int cur = 0;

    for (int kt = kt0; kt <= kt1; kt++) {
      if (kt < kt1) STAGE(cur ^ 1, kt + 1);

      // ---- ALiBi bias: full recompute at item start & sign-mixed tiles;
      // else one add per element (|d| affine in kt).
      if (kt == kt0 || kt == qt || kt == qt + 1) {
        #pragma unroll
        for (int kf = 0; kf < 4; kf++) {
          const float dif = qgf - (float)(kt * 64 + kf * 16 + lg * 4);
          #pragma unroll
          for (int r = 0; r < 4; r++)
            bias[kf][r] = -slope2 * __builtin_fabsf(dif - (float)r);
        }
      } else {
        const float step = (kt < qt) ? binc : -binc;
        #pragma unroll
        for (int kf = 0; kf < 4; kf++)
          #pragma unroll
          for (int r = 0; r < 4; r++) bias[kf][r] += step;
      }

      // ---- QK^T swapped, exponent domain: e = Qs·K + bias (bias rides C-in)
      f32x4 ex[4];
      __builtin_amdgcn_s_setprio(1);
      #pragma unroll
      for (int kf = 0; kf < 4; kf++) {
        const short8 kb0 = *(const short8*)&lK[cur][kf * 16 + lr][((lg)     ^ swz) * 8];
        const short8 kb1 = *(const short8*)&lK[cur][kf * 16 + lr][((lg + 4) ^ swz) * 8];
        f32x4 z = __builtin_amdgcn_mfma_f32_16x16x32_bf16(kb0, qf0, bias[kf], 0, 0, 0);
        ex[kf]  = __builtin_amdgcn_mfma_f32_16x16x32_bf16(kb1, qf1, z, 0, 0, 0);
      }
      __builtin_amdgcn_s_setprio(0);

      // ---- mask (flags all-zero for all-ones mask: branch never taken)
      const int flagv = flags[flg_base + kt];
      if (flagv) {
        #pragma unroll
        for (int kf = 0; kf < 4; kf++)
          #pragma unroll
          for (int r = 0; r < 4; r++) {
            const int key = kt * 64 + kf * 16 + lg * 4 + r;
            if (mask[((size_t)b * Ss + qg) * Ss + key] == 0) ex[kf][r] = -3.0e38f;
          }
      }

      // ---- p = exp2(e); pack 4 bf16 -> one b64 LDS write per kf (XOR-banked)
      #pragma unroll
      for (int kf = 0; kf < 4; kf++) {
        short4v pkv;
        #pragma unroll
        for (int r = 0; r < 4; r++) {
          const float pv = exp2f(ex[kf][r]);
          pkv[r] = (short)(u16)((__float_as_uint(pv) + 0x8000u) >> 16);
        }
        *(short4v*)(lpb + lr * 128 + ((kf * 32 + lg * 8) ^ sxor)) = pkv;
      }

      // same-wave DS write->read ordering (rule 18)
      asm volatile("s_waitcnt lgkmcnt(0)" ::: "memory");
      __builtin_amdgcn_sched_barrier(0);

      // ---- PV swapped + ones-MFMA row-sum
      const short8 pf0 = *(const short8*)(lpb + lr * 128 + ((lg * 16) ^ sxor));
      const short8 pf1 = *(const short8*)(lpb + lr * 128 + ((64 + lg * 16) ^ sxor));
      __builtin_amdgcn_s_setprio(1);
      #pragma unroll
      for (int nf = 0; nf < 4; nf++) {
        const short8 va0 = *(const short8*)&lV[cur][nf * 16 + lr][((lg)     ^ swz) * 8];
        const short8 va1 = *(const short8*)&lV[cur][nf * 16 + lr][((lg + 4) ^ swz) * 8];
        accO[nf] = __builtin_amdgcn_mfma_f32_16x16x32_bf16(va0, pf0, accO[nf], 0, 0, 0);
        accO[nf] = __builtin_amdgcn_mfma_f32_16x16x32_bf16(va1, pf1, accO[nf], 0, 0, 0);
      }
      acc5 = __builtin_amdgcn_mfma_f32_16x16x32_bf16(ones, pf0, acc5, 0, 0, 0);
      acc5 = __builtin_amdgcn_mfma_f32_16x16x32_bf16(ones, pf1, acc5, 0, 0, 0);
      __builtin_amdgcn_s_setprio(0);

      __syncthreads();   // drains vmcnt (next tile staged) + read/overwrite fence
      cur ^= 1;
    }
    #undef STAGE

    if (!split) {
      // full item: normalize + write AO (bf16)
      const float rinv = 1.0f / acc5[0];
      u16* aop = AO + (size_t)(b * Ss + qt * 64 + w * 16 + lr) * Dd + h * DKk;
      #pragma unroll
      for (int nf = 0; nf < 4; nf++) {
        short4v ov;
        #pragma unroll
        for (int r = 0; r < 4; r++) ov[r] = (short)f2bf(accO[nf][r] * rinv);
        *(short4v*)(aop + nf * 16 + lg * 4) = ov;
      }
    } else {
      // half item: write f32 partials. Pacc[p][b][h-8][s][dk], Sacc[p][b][h-8][s]
      const size_t rowid = (((size_t)p * 2 + b) * 8 + (h - 8)) * Ss + qt * 64 + w * 16 + lr;
      float* pb = Pacc + rowid * DKk;
      #pragma unroll
      for (int nf = 0; nf < 4; nf++)
        *(f32x4*)(pb + nf * 16 + lg * 4) = accO[nf];
      if (lg == 0) Sacc[rowid] = acc5[0];
    }
    // LDS safe to reuse: loop's final __syncthreads precedes epilogue (no LDS)
  }
}

// ---------------------------------------------------------------------------
// 5b) Combine split-K halves for h>=8: AO = (P0+P1)/(l0+l1).
// 32768 rows (b,h8,s); 16 threads/row, 16 rows/block -> 2048 blocks.
// ---------------------------------------------------------------------------
__global__ __launch_bounds__(256) void attn_norm(
    const float* __restrict__ Pacc, const float* __restrict__ Sacc,
    u16* __restrict__ AO)
{
  const int R  = blockIdx.x * 16 + (threadIdx.x >> 4);  // [0, 32768)
  const int dq = (threadIdx.x & 15) * 4;
  const float l = Sacc[R] + Sacc[32768 + R];
  const float rinv = 1.0f / l;
  const f32x4 a = *(const f32x4*)(Pacc + (size_t)R * 64 + dq);
  const f32x4 c = *(const f32x4*)(Pacc + (size_t)32768 * 64 + (size_t)R * 64 + dq);
  short4v o;
  #pragma unroll
  for (int r = 0; r < 4; r++) o[r] = (short)f2bf((a[r] + c[r]) * rinv);
  const int s = R & 2047, h8 = (R >> 11) & 7, b = R >> 14;
  *(short4v*)(AO + ((size_t)b * Ss + s) * Dd + (h8 + 8) * 64 + dq) = o;
}

// ---------------------------------------------------------------------------
// 6) Output projection — 2-phase dbuf + XCD-chunked grid (256 blocks, 32/XCD).
// ---------------------------------------------------------------------------
__global__ __launch_bounds__(256, 4) void gemm_out(
    const u16* __restrict__ A, const u16* __restrict__ Bw,
    const float* __restrict__ bo, float* __restrict__ out)
{
  const int bid   = blockIdx.x;
  const int swzid = (bid & 7) * 32 + (bid >> 3);   // 256 % 8 == 0, bijective
  const int mbase = (swzid >> 3) * 128, nbase = (swzid & 7) * 128;

  __shared__ u16 lA[2][128][32];
  __shared__ u16 lB[2][128][32];
  const int t = threadIdx.x, lane = t & 63, w = t >> 6;
  const int wr = w >> 1, wc = w & 1, lg = lane >> 4, lr = lane & 15;
  const int srow = lane >> 2, scol = (lane & 3) * 8;

  f32x4 acc[4][4];
  #pragma unroll
  for (int mf = 0; mf < 4; mf++)
    #pragma unroll
    for (int nf = 0; nf < 4; nf++) acc[mf][nf] = (f32x4){0.f, 0.f, 0.f, 0.f};

  const u16* ga0 = A  + (size_t)(mbase + w * 16       + srow) * Dd + scol;
  const u16* ga1 = A  + (size_t)(mbase + (w + 4) * 16 + srow) * Dd + scol;
  const u16* gb0 = Bw + (size_t)(nbase + w * 16       + srow) * Dd + scol;
  const u16* gb1 = Bw + (size_t)(nbase + (w + 4) * 16 + srow) * Dd + scol;

  #define GSTAGE(buf, kk_)                              \
    {                                                   \
      gl_lds16(ga0 + (kk_), &lA[buf][w * 16][0]);       \
      gl_lds16(ga1 + (kk_), &lA[buf][(w + 4) * 16][0]); \
      gl_lds16(gb0 + (kk_), &lB[buf][w * 16][0]);       \
      gl_lds16(gb1 + (kk_), &lB[buf][(w + 4) * 16][0]); \
    }

  GSTAGE(0, 0);
  __syncthreads();
  int cur = 0;

  for (int kk = 0; kk < Dd; kk += 32) {
    if (kk + 32 < Dd) GSTAGE(cur ^ 1, kk + 32);
    short8 af[4], bfr[4];
    #pragma unroll
    for (int mf = 0; mf < 4; mf++) af[mf]  = *(const short8*)&lA[cur][wr * 64 + mf * 16 + lr][lg * 8];
    #pragma unroll
    for (int nf = 0; nf < 4; nf++) bfr[nf] = *(const short8*)&lB[cur][wc * 64 + nf * 16 + lr][lg * 8];
    __builtin_amdgcn_s_setprio(1);
    #pragma unroll
    for (int mf = 0; mf < 4; mf++)
      #pragma unroll
      for (int nf = 0; nf < 4; nf++)
        acc[mf][nf] = __builtin_amdgcn_mfma_f32_16x16x32_bf16(af[mf], bfr[nf], acc[mf][nf], 0, 0, 0);
    __builtin_amdgcn_s_setprio(0);
    __syncthreads();
    cur ^= 1;
  }
  #undef GSTAGE

  #pragma unroll
  for (int nf = 0; nf < 4; nf++) {
    const int n = nbase + wc * 64 + nf * 16 + lr;
    const float bb = bo[n];
    #pragma unroll
    for (int mf = 0; mf < 4; mf++) {
      const int m0 = mbase + wr * 64 + mf * 16 + lg * 4;
      #pragma unroll
      for (int r = 0; r < 4; r++)
        out[(size_t)(m0 + r) * Dd + n] = acc[mf][nf][r] + bb;
    }
  }
}

// ---------------------------------------------------------------------------
extern "C" void kernel_launch(void* const* d_in, const int* in_sizes, int n_in,
                              void* d_out, int out_size, void* d_ws, size_t ws_size,
                              hipStream_t stream)
{
  (void)in_sizes; (void)n_in; (void)out_size; (void)ws_size;
  const float* q    = (const float*)d_in[0];
  const float* k    = (const float*)d_in[1];
  const float* v    = (const float*)d_in[2];
  const int*   mask = (const int*)  d_in[3];
  const float* Wq   = (const float*)d_in[4];
  const float* bq   = (const float*)d_in[5];
  const float* Wk   = (const float*)d_in[6];
  const float* bk   = (const float*)d_in[7];
  const float* Wv   = (const float*)d_in[8];
  const float* bv   = (const float*)d_in[9];
  const float* Wo   = (const float*)d_in[10];
  const float* bo   = (const float*)d_in[11];

  char* ws = (char*)d_ws;
  // ws+0 .. 25165824: split-K partials (Pacc/Sacc)
  u16* WT    = (u16*)(ws + 25165824);   // 4 * 1024*1024 bf16 =  8388608 B
  u16* Qh    = (u16*)(ws + 33554432);   // 8388608 B
  u16* Kh    = (u16*)(ws + 41943040);   // 8388608 B
  u16* Vt    = (u16*)(ws + 50331648);   // 8388608 B
  u16* AO    = (u16*)(ws + 58720256);   // 8388608 B
  int* flags = (int*)(ws + 67108864);   // 2048 * 4 B
  float* Pacc = (float*)(ws + 0);          // [2][2][8][2048][64] f32 = 16 MB
  float* Sacc = (float*)(ws + 16777216);   // [2][2][8][2048]     f32 = 256 KB

  prep        <<<3072, 256, 0, stream>>>(Wq, Wk, Wv, Wo, WT, mask, flags);
  gemm_qkv    <<<768, 256, 0, stream>>>(q, k, v, WT, bq, bk, bv, Qh, Kh, Vt);
  attn_kernel <<<1024, 256, 0, stream>>>(Qh, Kh, Vt, mask, flags, Pacc, Sacc, AO);
  attn_norm   <<<2048, 256, 0, stream>>>(Pacc, Sacc, AO);
  gemm_out    <<<256, 256, 0, stream>>>(AO, WT + (size_t)3 * Dd * Dd, bo, (float*)d_out);
}

// Round 21
// 118.885 us; speedup vs baseline: 1.0819x; 1.0245x over previous
//
#include <hip/hip_runtime.h>
#include <hip/hip_bf16.h>
#include <math.h>

// Problem constants (B,S,D,H fixed by the reference)
constexpr int Bb  = 2;
constexpr int Ss  = 2048;
constexpr int Dd  = 1024;
constexpr int Hh  = 16;
constexpr int DKk = 64;
constexpr int Mm  = Bb * Ss;   // 4096 rows

// Q pre-scale: log2(e)/sqrt(dk) -> QK MFMA output is directly the softmax
// exponent (base-2) before the ALiBi bias.
#define QSCALE 0.18033688f

typedef unsigned short u16;
typedef unsigned int   u32;
typedef __attribute__((ext_vector_type(8))) short short8;   // 8 bf16 = 16B (MFMA frag)
typedef __attribute__((ext_vector_type(4))) short short4v;  // 8B
typedef __attribute__((ext_vector_type(4))) float f32x4;
typedef __attribute__((ext_vector_type(4))) int   int4v;

static __device__ __forceinline__ u16 f2bf(float f) {
  union { float f; unsigned u; } c; c.f = f;
  unsigned u = c.u;
  unsigned r = u + 0x7FFFu + ((u >> 16) & 1u);  // RNE
  return (u16)(r >> 16);
}

// HW packed fp32x2 -> bf16x2 (RNE); elem a -> low 16 bits
static __device__ __forceinline__ u32 pk2(float a, float b) {
  __hip_bfloat162 t = __float22bfloat162_rn(float2{a, b});
  union { __hip_bfloat162 h; u32 u; } c; c.h = t;
  return c.u;
}

// async global->LDS, 16B per lane. LDS dest wave-uniform (HW adds lane*16).
static __device__ __forceinline__ void gl_lds16(const void* g, void* l) {
  __builtin_amdgcn_global_load_lds(
      (const __attribute__((address_space(1))) u32*)g,
      (__attribute__((address_space(3))) u32*)l, 16, 0, 0);
}

// ---------------------------------------------------------------------------
// 1) prep: wt_transpose (blocks 0..1023) + mask_flags (blocks 1024..3071).
// ---------------------------------------------------------------------------
__global__ __launch_bounds__(256) void prep(
    const float* __restrict__ wq, const float* __restrict__ wk,
    const float* __restrict__ wv, const float* __restrict__ wo,
    u16* __restrict__ outWT,
    const int* __restrict__ mask, int* __restrict__ flags)
{
  const int bid = blockIdx.x;
  const int t = threadIdx.x;
  if (bid < 1024) {
    // ---- weight transpose: WT[z][n][k] = W_z[k][n] as bf16
    __shared__ float tile[64][65];
    const int z = bid >> 8;
    const float* w = (z == 0) ? wq : (z == 1) ? wk : (z == 2) ? wv : wo;
    const int n0 = (bid & 15) * 64, k0 = ((bid >> 4) & 15) * 64;
    {
      const int r = t >> 2, u = t & 3;
      #pragma unroll
      for (int e = 0; e < 4; e++) {
        f32x4 f = *(const f32x4*)(w + (size_t)(k0 + r) * Dd + n0 + u * 16 + e * 4);
        tile[r][u * 16 + e * 4 + 0] = f[0];
        tile[r][u * 16 + e * 4 + 1] = f[1];
        tile[r][u * 16 + e * 4 + 2] = f[2];
        tile[r][u * 16 + e * 4 + 3] = f[3];
      }
    }
    __syncthreads();
    {
      const int n = t >> 2, u = t & 3;
      u16 tmp[16];
      #pragma unroll
      for (int e = 0; e < 16; e++) tmp[e] = f2bf(tile[u * 16 + e][n]);
      short8 o0, o1;
      #pragma unroll
      for (int j = 0; j < 8; j++) { o0[j] = (short)tmp[j]; o1[j] = (short)tmp[8 + j]; }
      u16* dst = outWT + (size_t)z * Dd * Dd + (size_t)(n0 + n) * Dd + k0 + u * 16;
      *(short8*)dst       = o0;
      *(short8*)(dst + 8) = o1;
    }
  } else {
    // ---- mask flags: flag[b][qt64][kt64] = any zero in 64x64 tile
    const int fid = bid - 1024;
    const int b = fid >> 10, qt = (fid >> 5) & 31, kt = fid & 31;
    int hasz = 0;
    #pragma unroll
    for (int e = 0; e < 4; e++) {
      int c = t + 256 * e;
      int row = c >> 4, c4 = c & 15;
      int4v mv = *(const int4v*)(mask + ((size_t)b * Ss + qt * 64 + row) * Ss + kt * 64 + c4 * 4);
      hasz |= (mv[0] == 0) | (mv[1] == 0) | (mv[2] == 0) | (mv[3] == 0);
    }
    __shared__ int red;
    if (t == 0) red = 0;
    __syncthreads();
    if (hasz) atomicOr(&red, 1);
    __syncthreads();
    if (t == 0) flags[fid] = red;
  }
}

// ---------------------------------------------------------------------------
// 4) Fused QKV projection GEMM, fp32-A-in-LDS (r18 arrangement, best measured).
// A staged RAW fp32 via global_load_lds (chunk-swizzled source, rule 21);
// fragments converted LDS-f32 -> bf16 with HW packed cvt. B: gl_lds bf16
// from WT. LDS 48KB -> 3 blocks/CU (= grid 768, fully resident).
// z=0 -> Qh PRE-SCALED by QSCALE, z=1 -> Kh, z=2 -> Vt[b][h][dk][s]
// ---------------------------------------------------------------------------
__global__ __launch_bounds__(256, 3) void gemm_qkv(
    const float* __restrict__ qin, const float* __restrict__ kin,
    const float* __restrict__ vin, const u16* __restrict__ WT,
    const float* __restrict__ bq, const float* __restrict__ bk,
    const float* __restrict__ bv,
    u16* __restrict__ Qh, u16* __restrict__ Kh, u16* __restrict__ Vt)
{
  // XCD-chunked bijective swizzle (768 % 8 == 0): xcd = bid%8 owns 96 ids
  const int bid   = blockIdx.x;
  const int swzid = (bid & 7) * 96 + (bid >> 3);
  const int z     = swzid >> 8;          // 256 blocks per z
  const int rem   = swzid & 255;
  const int mbase = (rem >> 3) * 128, nbase = (rem & 7) * 128;

  const float* Af = (z == 0) ? qin : (z == 1) ? kin : vin;
  const u16*   Bw = WT + (size_t)z * Dd * Dd;
  const float* bias = (z == 0) ? bq : (z == 1) ? bk : bv;

  __shared__ float lAf[2][128][32];   // raw fp32 A, chunk-swizzled (32 KB)
  __shared__ u16   lB[2][128][32];    // bf16 B (16 KB)

  const int t = threadIdx.x, lane = t & 63, w = t >> 6;
  const int wr = w >> 1, wc = w & 1, lg = lane >> 4, lr = lane & 15;
  const int srow = lane >> 2;          // B staging: row within 16-chunk
  const int scol = (lane & 3) * 8;     // B staging: u16 col within 32

  // A staging: lane -> (row8 = lane>>3, chunk = lane&7), SOURCE chunk swizzled
  const int arow8 = lane >> 3;                         // 0..7
  const int ascs  = ((lane & 7) ^ arow8) * 4;          // f32 col within 32
  // A fragment read: chunk indices XOR'd by (row&7) == (lr&7)
  const int aswz  = lr & 7;
  const int aoff0 = (((2 * lg)     ^ aswz) * 4);       // f32 idx within row
  const int aoff1 = (((2 * lg + 1) ^ aswz) * 4);

  f32x4 acc[4][4];
  #pragma unroll
  for (int mf = 0; mf < 4; mf++)
    #pragma unroll
    for (int nf = 0; nf < 4; nf++) acc[mf][nf] = (f32x4){0.f, 0.f, 0.f, 0.f};

  const u16* gb0 = Bw + (size_t)(nbase + w * 16       + srow) * Dd + scol;
  const u16* gb1 = Bw + (size_t)(nbase + (w + 4) * 16 + srow) * Dd + scol;

  #define GSTAGE(buf, kk_)                                                        \
    {                                                                             \
      _Pragma("unroll")                                                           \
      for (int j = 0; j < 4; j++) {                                               \
        const int row = mbase + j * 32 + w * 8 + arow8;                           \
        gl_lds16(Af + (size_t)row * Dd + (kk_) + ascs, &lAf[buf][j * 32 + w * 8][0]); \
      }                                                                           \
      gl_lds16(gb0 + (kk_), &lB[buf][w * 16][0]);                                 \
      gl_lds16(gb1 + (kk_), &lB[buf][(w + 4) * 16][0]);                           \
    }

  GSTAGE(0, 0);
  __syncthreads();
  int cur = 0;

  for (int kk = 0; kk < Dd; kk += 32) {
    if (kk + 32 < Dd) GSTAGE(cur ^ 1, kk + 32);
    // A fragments: read swizzled f32 pairs, HW-pack to bf16
    short8 af[4];
    #pragma unroll
    for (int mf = 0; mf < 4; mf++) {
      const float* arow = &lAf[cur][wr * 64 + mf * 16 + lr][0];
      const f32x4 c0 = *(const f32x4*)(arow + aoff0);
      const f32x4 c1 = *(const f32x4*)(arow + aoff1);
      int4v pv;
      pv[0] = (int)pk2(c0[0], c0[1]);
      pv[1] = (int)pk2(c0[2], c0[3]);
      pv[2] = (int)pk2(c1[0], c1[1]);
      pv[3] = (int)pk2(c1[2], c1[3]);
      af[mf] = *(short8*)&pv;
    }
    short8 bfr[4];
    #pragma unroll
    for (int nf = 0; nf < 4; nf++) bfr[nf] = *(const short8*)&lB[cur][wc * 64 + nf * 16 + lr][lg * 8];
    __builtin_amdgcn_s_setprio(1);
    #pragma unroll
    for (int mf = 0; mf < 4; mf++)
      #pragma unroll
      for (int nf = 0; nf < 4; nf++)
        acc[mf][nf] = __builtin_amdgcn_mfma_f32_16x16x32_bf16(af[mf], bfr[nf], acc[mf][nf], 0, 0, 0);
    __builtin_amdgcn_s_setprio(0);
    __syncthreads();   // reads of [cur] done + staged loads landed
    cur ^= 1;
  }
  #undef GSTAGE

  #pragma unroll
  for (int nf = 0; nf < 4; nf++) {
    const int n = nbase + wc * 64 + nf * 16 + lr;
    const float bb = bias[n];
    const int h = n >> 6, dk = n & 63;
    #pragma unroll
    for (int mf = 0; mf < 4; mf++) {
      const int m0 = mbase + wr * 64 + mf * 16 + lg * 4;
      const int b = m0 >> 11, s0 = m0 & 2047;
      if (z == 2) {
        short4v o;
        #pragma unroll
        for (int r = 0; r < 4; r++) o[r] = (short)f2bf(acc[mf][nf][r] + bb);
        *(short4v*)(Vt + ((size_t)(b * Hh + h) * DKk + dk) * Ss + s0) = o;
      } else if (z == 0) {
        // Q pre-scaled: exponent-domain QK (see attn_kernel)
        #pragma unroll
        for (int r = 0; r < 4; r++)
          Qh[((size_t)(b * Hh + h) * Ss + s0 + r) * DKk + dk] =
              f2bf((acc[mf][nf][r] + bb) * QSCALE);
      } else {
        #pragma unroll
        for (int r = 0; r < 4; r++)
          Kh[((size_t)(b * Hh + h) * Ss + s0 + r) * DKk + dk] = f2bf(acc[mf][nf][r] + bb);
      }
    }
  }
}

// ---------------------------------------------------------------------------
// 5) Flash attention with ALiBi — no-max softmax + bias-in-MFMA-C + SPLIT-K.
// Window margin 10 nats (r20, validated: absmax unchanged).
// ---------------------------------------------------------------------------
__global__ __launch_bounds__(256, 4) void attn_kernel(
    const u16* __restrict__ Qh, const u16* __restrict__ Kh, const u16* __restrict__ Vt,
    const int* __restrict__ mask, const int* __restrict__ flags,
    float* __restrict__ Pacc, float* __restrict__ Sacc, u16* __restrict__ AO)
{
  const int bid = blockIdx.x;
  const int t = threadIdx.x, lane = t & 63, w = t >> 6;
  const int lg = lane >> 4, lr = lane & 15;

  __shared__ u16 lK[2][64][64];   // [buf][key][dk], swizzled chunks (16 KB)
  __shared__ u16 lV[2][64][64];   // [buf][dk][key], swizzled chunks (16 KB)
  __shared__ u16 lP[4][16][64];   // per-wave P [q][key], XOR-banked (8 KB)

  const int swz  = lr & 7;         // XOR key for K/V fragment reads
  const int sxor = (lr & 7) << 4;  // byte-XOR key for lP (bits 4-6)
  char* lpb = (char*)&lP[w][0][0];

  // staging geometry: lane -> (row j*8 + (l>>3), linear chunk l&7), source swizzled
  const int srr = lane >> 3;                    // 0..7
  const int scs = ((lane & 7) ^ srr) * 8;       // swizzled source chunk (u16 offset)

  // ones fragment for row-sum MFMA (bf16 1.0 = 0x3F80)
  short8 ones;
  #pragma unroll
  for (int j = 0; j < 8; j++) ones[j] = (short)0x3F80;

  const int nit = (bid >= 512) ? 2 : 1;

  for (int it = 0; it < nit; ++it) {
    // ---- work-item decode (bijective; verified: each (b,h,qt[,p]) once)
    int b, h, qt, p, split;
    if (it == 0) {
      h = 15 - (bid >> 7);               // 8..15
      const int rem = bid & 127;
      b = rem >> 6; qt = (rem >> 1) & 31; p = rem & 1; split = 1;
    } else {
      const int sidx = bid - 512, group = sidx >> 7, within = sidx & 127;
      h = group * 2 + (within >> 6);     // 0..7
      b = (within >> 5) & 1; qt = within & 31; p = 0; split = 0;
    }

    const u16* Qp = Qh + ((size_t)(b * Hh + h) * Ss + qt * 64 + w * 16) * DKk;
    const u16* Kp = Kh + ((size_t)(b * Hh + h) * Ss) * DKk;
    const u16* Vp = Vt + ((size_t)(b * Hh + h) * DKk) * Ss;

    const short8 qf0 = *(const short8*)(Qp + lr * DKk + lg * 8);
    const short8 qf1 = *(const short8*)(Qp + lr * DKk + 32 + lg * 8);

    const float slope_n = exp2f(-0.5f * (float)(h + 1));
    const float slope2  = slope_n * 1.44269504f;
    const float binc    = 64.0f * slope2;

    // ALiBi window, margin 10 nats (tail ~4.5e-5 rel << bf16 ulp)
    const int W = (int)(__builtin_fmaf(0.3466f, (float)(h + 1), 10.0f) / slope_n);
    const int q0 = qt * 64;
    int kt0 = max(0, (q0 - W) >> 6);
    int kt1 = min((int)(Ss / 64) - 1, (q0 + 63 + W) >> 6);
    if (split) { const int mid = (kt0 + kt1 + 1) >> 1; if (p == 0) kt1 = mid - 1; else kt0 = mid; }

    f32x4 accO[4], acc5;
    #pragma unroll
    for (int nf = 0; nf < 4; nf++) accO[nf] = (f32x4){0.f, 0.f, 0.f, 0.f};
    acc5 = (f32x4){0.f, 0.f, 0.f, 0.f};

    const int   qg  = qt * 64 + w * 16 + lr;
    const float qgf = (float)qg;
    const int flg_base = (b * 32 + qt) * 32;
    f32x4 bias[4];

    #define STAGE(buf, kt_)                                                          \
      {                                                                              \
        _Pragma("unroll")                                                            \
        for (int j = 0; j < 2; j++) {                                                \
          const int row = w * 16 + j * 8 + srr;                                      \
          gl_lds16(Kp + (size_t)((kt_) * 64 + row) * DKk + scs, &lK[buf][w * 16 + j * 8][0]); \
          gl_lds16(Vp + (size_t)row * Ss + (kt_) * 64 + scs,    &lV[buf][w * 16 + j * 8][0]); \
        }                                                                            \
      }

    STAGE(0, kt0);
    __syncthreads();
    int cur = 0;

    for (int kt = kt0; kt <= kt1; kt++) {
      if (kt < kt1) STAGE(cur ^ 1, kt + 1);

      // ---- ALiBi bias: full recompute at item start & sign-mixed tiles;
      // else one add per element (|d| affine in kt).
      if (kt == kt0 || kt == qt || kt == qt + 1) {
        #pragma unroll
        for (int kf = 0; kf < 4; kf++) {
          const float dif = qgf - (float)(kt * 64 + kf * 16 + lg * 4);
          #pragma unroll
          for (int r = 0; r < 4; r++)
            bias[kf][r] = -slope2 * __builtin_fabsf(dif - (float)r);
        }
      } else {
        const float step = (kt < qt) ? binc : -binc;
        #pragma unroll
        for (int kf = 0; kf < 4; kf++)
          #pragma unroll
          for (int r = 0; r < 4; r++) bias[kf][r] += step;
      }

      // ---- QK^T swapped, exponent domain: e = Qs·K + bias (bias rides C-in)
      f32x4 ex[4];
      __builtin_amdgcn_s_setprio(1);
      #pragma unroll
      for (int kf = 0; kf < 4; kf++) {
        const short8 kb0 = *(const short8*)&lK[cur][kf * 16 + lr][((lg)     ^ swz) * 8];
        const short8 kb1 = *(const short8*)&lK[cur][kf * 16 + lr][((lg + 4) ^ swz) * 8];
        f32x4 z = __builtin_amdgcn_mfma_f32_16x16x32_bf16(kb0, qf0, bias[kf], 0, 0, 0);
        ex[kf]  = __builtin_amdgcn_mfma_f32_16x16x32_bf16(kb1, qf1, z, 0, 0, 0);
      }
      __builtin_amdgcn_s_setprio(0);

      // ---- mask (flags all-zero for all-ones mask: branch never taken)
      const int flagv = flags[flg_base + kt];
      if (flagv) {
        #pragma unroll
        for (int kf = 0; kf < 4; kf++)
          #pragma unroll
          for (int r = 0; r < 4; r++) {
            const int key = kt * 64 + kf * 16 + lg * 4 + r;
            if (mask[((size_t)b * Ss + qg) * Ss + key] == 0) ex[kf][r] = -3.0e38f;
          }
      }

      // ---- p = exp2(e); pack 4 bf16 -> one b64 LDS write per kf (XOR-banked)
      #pragma unroll
      for (int kf = 0; kf < 4; kf++) {
        short4v pkv;
        #pragma unroll
        for (int r = 0; r < 4; r++) {
          const float pv = exp2f(ex[kf][r]);
          pkv[r] = (short)(u16)((__float_as_uint(pv) + 0x8000u) >> 16);
        }
        *(short4v*)(lpb + lr * 128 + ((kf * 32 + lg * 8) ^ sxor)) = pkv;
      }

      // same-wave DS write->read ordering (rule 18)
      asm volatile("s_waitcnt lgkmcnt(0)" ::: "memory");
      __builtin_amdgcn_sched_barrier(0);

      // ---- PV swapped + ones-MFMA row-sum
      const short8 pf0 = *(const short8*)(lpb + lr * 128 + ((lg * 16) ^ sxor));
      const short8 pf1 = *(const short8*)(lpb + lr * 128 + ((64 + lg * 16) ^ sxor));
      __builtin_amdgcn_s_setprio(1);
      #pragma unroll
      for (int nf = 0; nf < 4; nf++) {
        const short8 va0 = *(const short8*)&lV[cur][nf * 16 + lr][((lg)     ^ swz) * 8];
        const short8 va1 = *(const short8*)&lV[cur][nf * 16 + lr][((lg + 4) ^ swz) * 8];
        accO[nf] = __builtin_amdgcn_mfma_f32_16x16x32_bf16(va0, pf0, accO[nf], 0, 0, 0);
        accO[nf] = __builtin_amdgcn_mfma_f32_16x16x32_bf16(va1, pf1, accO[nf], 0, 0, 0);
      }
      acc5 = __builtin_amdgcn_mfma_f32_16x16x32_bf16(ones, pf0, acc5, 0, 0, 0);
      acc5 = __builtin_amdgcn_mfma_f32_16x16x32_bf16(ones, pf1, acc5, 0, 0, 0);
      __builtin_amdgcn_s_setprio(0);

      __syncthreads();   // drains vmcnt (next tile staged) + read/overwrite fence
      cur ^= 1;
    }
    #undef STAGE

    if (!split) {
      // full item: normalize + write AO (bf16)
      const float rinv = 1.0f / acc5[0];
      u16* aop = AO + (size_t)(b * Ss + qt * 64 + w * 16 + lr) * Dd + h * DKk;
      #pragma unroll
      for (int nf = 0; nf < 4; nf++) {
        short4v ov;
        #pragma unroll
        for (int r = 0; r < 4; r++) ov[r] = (short)f2bf(accO[nf][r] * rinv);
        *(short4v*)(aop + nf * 16 + lg * 4) = ov;
      }
    } else {
      // half item: write f32 partials. Pacc[p][b][h-8][s][dk], Sacc[p][b][h-8][s]
      const size_t rowid = (((size_t)p * 2 + b) * 8 + (h - 8)) * Ss + qt * 64 + w * 16 + lr;
      float* pb = Pacc + rowid * DKk;
      #pragma unroll
      for (int nf = 0; nf < 4; nf++)
        *(f32x4*)(pb + nf * 16 + lg * 4) = accO[nf];
      if (lg == 0) Sacc[rowid] = acc5[0];
    }
    // LDS safe to reuse: loop's final __syncthreads precedes epilogue (no LDS)
  }
}

// ---------------------------------------------------------------------------
// 5b) Combine split-K halves for h>=8: AO = (P0+P1)/(l0+l1).
// 32768 rows (b,h8,s); 16 threads/row, 16 rows/block -> 2048 blocks.
// ---------------------------------------------------------------------------
__global__ __launch_bounds__(256) void attn_norm(
    const float* __restrict__ Pacc, const float* __restrict__ Sacc,
    u16* __restrict__ AO)
{
  const int R  = blockIdx.x * 16 + (threadIdx.x >> 4);  // [0, 32768)
  const int dq = (threadIdx.x & 15) * 4;
  const float l = Sacc[R] + Sacc[32768 + R];
  const float rinv = 1.0f / l;
  const f32x4 a = *(const f32x4*)(Pacc + (size_t)R * 64 + dq);
  const f32x4 c = *(const f32x4*)(Pacc + (size_t)32768 * 64 + (size_t)R * 64 + dq);
  short4v o;
  #pragma unroll
  for (int r = 0; r < 4; r++) o[r] = (short)f2bf((a[r] + c[r]) * rinv);
  const int s = R & 2047, h8 = (R >> 11) & 7, b = R >> 14;
  *(short4v*)(AO + ((size_t)b * Ss + s) * Dd + (h8 + 8) * 64 + dq) = o;
}

// ---------------------------------------------------------------------------
// 6) Output projection — r21: 128x64 tiles, grid 512 = 2 blocks/CU (was 256
// = 1 block/CU = 1 wave/SIMD, zero latency hiding). LDS 24KB. Wave w owns
// rows w*32..w*32+31 (mf 0..1), all 64 cols (nf 0..3). XCD-chunked swizzle
// (512%8==0); 16 consecutive ids = one full M-row per XCD chunk.
// ---------------------------------------------------------------------------
__global__ __launch_bounds__(256, 4) void gemm_out(
    const u16* __restrict__ A, const u16* __restrict__ Bw,
    const float* __restrict__ bo, float* __restrict__ out)
{
  const int bid   = blockIdx.x;
  const int swzid = (bid & 7) * 64 + (bid >> 3);   // 512 % 8 == 0, bijective
  const int mbase = (swzid >> 4) * 128, nbase = (swzid & 15) * 64;

  __shared__ u16 lA[2][128][32];   // 16 KB
  __shared__ u16 lB[2][64][32];    //  8 KB
  const int t = threadIdx.x, lane = t & 63, w = t >> 6;
  const int lg = lane >> 4, lr = lane & 15;
  const int srow = lane >> 2, scol = (lane & 3) * 8;

  f32x4 acc[2][4];
  #pragma unroll
  for (int mf = 0; mf < 2; mf++)
    #pragma unroll
    for (int nf = 0; nf < 4; nf++) acc[mf][nf] = (f32x4){0.f, 0.f, 0.f, 0.f};

  const u16* ga0 = A  + (size_t)(mbase + w * 32      + srow) * Dd + scol;
  const u16* ga1 = A  + (size_t)(mbase + w * 32 + 16 + srow) * Dd + scol;
  const u16* gb0 = Bw + (size_t)(nbase + w * 16      + srow) * Dd + scol;

  #define GSTAGE(buf, kk_)                                   \
    {                                                        \
      gl_lds16(ga0 + (kk_), &lA[buf][w * 32][0]);            \
      gl_lds16(ga1 + (kk_), &lA[buf][w * 32 + 16][0]);       \
      gl_lds16(gb0 + (kk_), &lB[buf][w * 16][0]);            \
    }

  GSTAGE(0, 0);
  __syncthreads();
  int cur = 0;

  for (int kk = 0; kk < Dd; kk += 32) {
    if (kk + 32 < Dd) GSTAGE(cur ^ 1, kk + 32);
    short8 af[2], bfr[4];
    #pragma unroll
    for (int mf = 0; mf < 2; mf++) af[mf]  = *(const short8*)&lA[cur][w * 32 + mf * 16 + lr][lg * 8];
    #pragma unroll
    for (int nf = 0; nf < 4; nf++) bfr[nf] = *(const short8*)&lB[cur][nf * 16 + lr][lg * 8];
    __builtin_amdgcn_s_setprio(1);
    #pragma unroll
    for (int mf = 0; mf < 2; mf++)
      #pragma unroll
      for (int nf = 0; nf < 4; nf++)
        acc[mf][nf] = __builtin_amdgcn_mfma_f32_16x16x32_bf16(af[mf], bfr[nf], acc[mf][nf], 0, 0, 0);
    __builtin_amdgcn_s_setprio(0);
    __syncthreads();
    cur ^= 1;
  }
  #undef GSTAGE

  #pragma unroll
  for (int nf = 0; nf < 4; nf++) {
    const int n = nbase + nf * 16 + lr;
    const float bb = bo[n];
    #pragma unroll
    for (int mf = 0; mf < 2; mf++) {
      const int m0 = mbase + w * 32 + mf * 16 + lg * 4;
      #pragma unroll
      for (int r = 0; r < 4; r++)
        out[(size_t)(m0 + r) * Dd + n] = acc[mf][nf][r] + bb;
    }
  }
}

// ---------------------------------------------------------------------------
extern "C" void kernel_launch(void* const* d_in, const int* in_sizes, int n_in,
                              void* d_out, int out_size, void* d_ws, size_t ws_size,
                              hipStream_t stream)
{
  (void)in_sizes; (void)n_in; (void)out_size; (void)ws_size;
  const float* q    = (const float*)d_in[0];
  const float* k    = (const float*)d_in[1];
  const float* v    = (const float*)d_in[2];
  const int*   mask = (const int*)  d_in[3];
  const float* Wq   = (const float*)d_in[4];
  const float* bq   = (const float*)d_in[5];
  const float* Wk   = (const float*)d_in[6];
  const float* bk   = (const float*)d_in[7];
  const float* Wv   = (const float*)d_in[8];
  const float* bv   = (const float*)d_in[9];
  const float* Wo   = (const float*)d_in[10];
  const float* bo   = (const float*)d_in[11];

  char* ws = (char*)d_ws;
  // ws+0 .. 25165824: split-K partials (Pacc/Sacc)
  u16* WT    = (u16*)(ws + 25165824);   // 4 * 1024*1024 bf16 =  8388608 B
  u16* Qh    = (u16*)(ws + 33554432);   // 8388608 B
  u16* Kh    = (u16*)(ws + 41943040);   // 8388608 B
  u16* Vt    = (u16*)(ws + 50331648);   // 8388608 B
  u16* AO    = (u16*)(ws + 58720256);   // 8388608 B
  int* flags = (int*)(ws + 67108864);   // 2048 * 4 B
  float* Pacc = (float*)(ws + 0);          // [2][2][8][2048][64] f32 = 16 MB
  float* Sacc = (float*)(ws + 16777216);   // [2][2][8][2048]     f32 = 256 KB

  prep        <<<3072, 256, 0, stream>>>(Wq, Wk, Wv, Wo, WT, mask, flags);
  gemm_qkv    <<<768, 256, 0, stream>>>(q, k, v, WT, bq, bk, bv, Qh, Kh, Vt);
  attn_kernel <<<1024, 256, 0, stream>>>(Qh, Kh, Vt, mask, flags, Pacc, Sacc, AO);
  attn_norm   <<<2048, 256, 0, stream>>>(Pacc, Sacc, AO);
  gemm_out    <<<512, 256, 0, stream>>>(AO, WT + (size_t)3 * Dd * Dd, bo, (float*)d_out);
}